// Round 1
// baseline (222.124 us; speedup 1.0000x reference)
//
#include <hip/hip_runtime.h>

typedef unsigned int uint;
typedef unsigned short ushort;

#define IN_C 128
#define HID  32

// ---- f16 helpers (fp32 accumulate everywhere; RNE on store) ---------------
// pack two f32 -> packed f16x2 (RNE via v_cvt_f16_f32)
__device__ __forceinline__ uint f2h2(float a, float b) {
    _Float16 ha = (_Float16)a, hb = (_Float16)b;
    unsigned short ua = __builtin_bit_cast(unsigned short, ha);
    unsigned short ub = __builtin_bit_cast(unsigned short, hb);
    return (uint)ua | ((uint)ub << 16);
}
// acc += f16_lo(pk) * v  -- single full-rate VOP3P v_fma_mix_f32, no unpack
__device__ __forceinline__ void fma_lo(float& acc, uint pk, float v) {
    asm("v_fma_mix_f32 %0, %1, %2, %0 op_sel:[0,0,0] op_sel_hi:[1,0,0]"
        : "+v"(acc) : "v"(pk), "v"(v));
}
// acc += f16_hi(pk) * v
__device__ __forceinline__ void fma_hi(float& acc, uint pk, float v) {
    asm("v_fma_mix_f32 %0, %1, %2, %0 op_sel:[1,0,0] op_sel_hi:[1,0,0]"
        : "+v"(acc) : "v"(pk), "v"(v));
}

// ---------------------------------------------------------------------------
// K1: fused prep.
//   blocks [0,nbE)            : r0 = relu(x @ w_embed) -> f16
//   blocks [nbE,nbE+nbI)      : both CSR indptrs by binary search
//   blocks [nbE+nbI, +nbT)    : warm-touch A2 col/val into LLC (overlaps the
//                               latency-bound searches; lvl-1 then reads warm)
// ---------------------------------------------------------------------------
__global__ void prep_kernel(const float* __restrict__ x,
                            const float* __restrict__ w,
                            ushort* __restrict__ r0,
                            const int* __restrict__ a1r, int E1, int* __restrict__ ip1,
                            const int* __restrict__ a2r, int E2, int* __restrict__ ip2,
                            const int* __restrict__ a2c, const float* __restrict__ a2v,
                            float* __restrict__ dummy,
                            int n, int nbE, int nbI, int nbT) {
    __shared__ float wl[IN_C * HID];
    const int tid = threadIdx.x;
    if (blockIdx.x < nbE) {
        for (int i = tid; i < IN_C * HID; i += blockDim.x) wl[i] = w[i];
        __syncthreads();
        const int row = blockIdx.x * 16 + tid / 16;
        const int h0  = (tid % 16) * 2;
        if (row >= n) return;
        const float4* xr = (const float4*)(x + (size_t)row * IN_C);
        float a0 = 0.f, a1 = 0.f;
#pragma unroll
        for (int k4 = 0; k4 < IN_C / 4; ++k4) {
            float4 xv = xr[k4];
            a0 += xv.x * wl[(4*k4+0)*HID + h0];  a1 += xv.x * wl[(4*k4+0)*HID + h0+1];
            a0 += xv.y * wl[(4*k4+1)*HID + h0];  a1 += xv.y * wl[(4*k4+1)*HID + h0+1];
            a0 += xv.z * wl[(4*k4+2)*HID + h0];  a1 += xv.z * wl[(4*k4+2)*HID + h0+1];
            a0 += xv.w * wl[(4*k4+3)*HID + h0];  a1 += xv.w * wl[(4*k4+3)*HID + h0+1];
        }
        uint p = f2h2(fmaxf(a0, 0.f), fmaxf(a1, 0.f));
        ((uint*)r0)[(size_t)row * 16 + (tid % 16)] = p;
    } else if (blockIdx.x < nbE + nbI) {
        const int i = (blockIdx.x - nbE) * 256 + tid;
        if (i > n) return;
        int lo = 0, hi = E1;
        while (lo < hi) { int m = (lo + hi) >> 1; if (a1r[m] < i) lo = m + 1; else hi = m; }
        ip1[i] = lo;
        lo = 0; hi = E2;
        while (lo < hi) { int m = (lo + hi) >> 1; if (a2r[m] < i) lo = m + 1; else hi = m; }
        ip2[i] = lo;
    } else {
        // warm-touch A2 edge arrays (coalesced stream; result dummy-used)
        const int t = (blockIdx.x - nbE - nbI) * 256 + tid;
        const int stride = nbT * 256;
        const int total4 = E2 / 4;
        const float4* c4 = (const float4*)a2c;
        const float4* v4 = (const float4*)a2v;
        float s = 0.f;
        for (int i = t; i < total4; i += stride) {
            float4 u = c4[i], v = v4[i];
            s += u.x + u.y + u.z + u.w + v.x + v.y + v.z + v.w;
        }
        if (s == 123.456f) dummy[0] = s;   // never true in practice; defeats DCE
    }
}

// ---------------------------------------------------------------------------
// K2: fused-level SpMM + ReLU, f16 features / fp32 accumulate via
// v_fma_mix_f32 (1 VALU per feature-MAC, no unpack).
// ROWS rows per wave; per row: L = C/8 feature-lanes (uint4 = 8 f16 feats)
// x W edge-ways, 4-edge int4/float4 batches (R4 structure: VGPR ~32, max
// occupancy — TLP beats per-wave ILP here; widening regressed previously).
// Gathers use 32-bit voffset + SGPR base (single v_lshl_add for addressing).
// Blocks [0,nb2) = A2 (heavy, out col off C); rest = A1 (off 0).
// ---------------------------------------------------------------------------
template <int C, int ROWS>
__global__ __launch_bounds__(256) void spmm_level(
        const int* __restrict__ ip1, const int* __restrict__ col1,
        const float* __restrict__ val1,
        const int* __restrict__ ip2, const int* __restrict__ col2,
        const float* __restrict__ val2,
        const ushort* __restrict__ xin, ushort* __restrict__ out,
        int n, int nb2) {
    constexpr int L    = C / 8;        // feature lanes per row
    constexpr int SUBL = 64 / ROWS;    // lanes per row
    constexpr int W    = SUBL / L;     // edge ways per row
    const int lane = threadIdx.x & 63;
    const int wave = threadIdx.x >> 6;
    const int sub  = lane / SUBL;
    const int li   = lane % SUBL;
    const int fl   = li % L;
    const int way  = li / L;

    int bid = blockIdx.x;
    const int* ip; const int* col; const float* val; int off;
    if (bid < nb2) {             ip = ip2; col = col2; val = val2; off = C; }
    else           { bid -= nb2; ip = ip1; col = col1; val = val1; off = 0; }

    const int row = (bid * 4 + wave) * ROWS + sub;
    if (row >= n) return;

    const uint flo = (uint)fl * 16u;   // byte offset of this lane's 8 feats
    float acc[8];
#pragma unroll
    for (int j = 0; j < 8; ++j) acc[j] = 0.f;

    auto gat = [&](uint c) -> uint4 {
        // 32-bit offset: c*(2C) + flo  (max ~2.5MB, fits easily)
        return *(const uint4*)((const char*)xin + (c * (uint)(2 * C) + flo));
    };
    auto fmadd = [&](const uint4& u, float v) {
        fma_lo(acc[0], u.x, v); fma_hi(acc[1], u.x, v);
        fma_lo(acc[2], u.y, v); fma_hi(acc[3], u.y, v);
        fma_lo(acc[4], u.z, v); fma_hi(acc[5], u.z, v);
        fma_lo(acc[6], u.w, v); fma_hi(acc[7], u.w, v);
    };

    const int s = ip[row];
    const int e = ip[row + 1];
    int sv = (s + 3) & ~3; if (sv > e) sv = e;     // 16B-align vector loads
    const int nv = (e - sv) / (4 * W);

    // unaligned head (<=3 edges)
    for (int idx = s + way; idx < sv; idx += W) fmadd(gat((uint)col[idx]), val[idx]);

    // vector body: 4 edges per way per iteration
    const int*   cb = col + sv;
    const float* vb = val + sv;
    for (int i = 0; i < nv; ++i) {
        const int base = (i * W + way) * 4;
        const int4   cc = *(const int4*)  (cb + base);
        const float4 vv = *(const float4*)(vb + base);
        const uint4 g0 = gat((uint)cc.x), g1 = gat((uint)cc.y),
                    g2 = gat((uint)cc.z), g3 = gat((uint)cc.w);
        fmadd(g0, vv.x); fmadd(g1, vv.y); fmadd(g2, vv.z); fmadd(g3, vv.w);
    }
    // scalar tail
    for (int idx = sv + nv * 4 * W + way; idx < e; idx += W)
        fmadd(gat((uint)col[idx]), val[idx]);

    // cross-way in-register reduction (stays within each row's subgroup)
#pragma unroll
    for (int m = L; m < SUBL; m <<= 1)
#pragma unroll
        for (int j = 0; j < 8; ++j) acc[j] += __shfl_xor(acc[j], m, 64);

    if (way == 0) {
        uint4 p;
        p.x = f2h2(fmaxf(acc[0], 0.f), fmaxf(acc[1], 0.f));
        p.y = f2h2(fmaxf(acc[2], 0.f), fmaxf(acc[3], 0.f));
        p.z = f2h2(fmaxf(acc[4], 0.f), fmaxf(acc[5], 0.f));
        p.w = f2h2(fmaxf(acc[6], 0.f), fmaxf(acc[7], 0.f));
        *(uint4*)(out + (size_t)row * (2 * C) + off + fl * 8) = p;
    }
}

// ---------------------------------------------------------------------------
// K3: out = [r0 | r1 | r2] @ w_classify  (f16 features via v_fma_mix,
// fp32 weights in LDS)
// ---------------------------------------------------------------------------
#define CDIM 224
#define OUT_C 16
__global__ void classify_kernel(const ushort* __restrict__ r0,
                                const ushort* __restrict__ r1,
                                const ushort* __restrict__ r2,
                                const float* __restrict__ w,
                                float* __restrict__ out, int n) {
    __shared__ float wl[CDIM * OUT_C];
    const int tid = threadIdx.x;
    for (int i = tid; i < CDIM * OUT_C; i += blockDim.x) wl[i] = w[i];
    __syncthreads();
    const int row = blockIdx.x * 16 + tid / 16;
    const int o   = tid % 16;
    if (row >= n) return;
    float acc = 0.f;

    const uint4* a = (const uint4*)(r0 + (size_t)row * 32);
#pragma unroll
    for (int q = 0; q < 4; ++q) {
        uint4 u = a[q]; int j = q * 8;
        fma_lo(acc, u.x, wl[(j+0)*OUT_C + o]);  fma_hi(acc, u.x, wl[(j+1)*OUT_C + o]);
        fma_lo(acc, u.y, wl[(j+2)*OUT_C + o]);  fma_hi(acc, u.y, wl[(j+3)*OUT_C + o]);
        fma_lo(acc, u.z, wl[(j+4)*OUT_C + o]);  fma_hi(acc, u.z, wl[(j+5)*OUT_C + o]);
        fma_lo(acc, u.w, wl[(j+6)*OUT_C + o]);  fma_hi(acc, u.w, wl[(j+7)*OUT_C + o]);
    }
    const uint4* b = (const uint4*)(r1 + (size_t)row * 64);
#pragma unroll
    for (int q = 0; q < 8; ++q) {
        uint4 u = b[q]; int j = 32 + q * 8;
        fma_lo(acc, u.x, wl[(j+0)*OUT_C + o]);  fma_hi(acc, u.x, wl[(j+1)*OUT_C + o]);
        fma_lo(acc, u.y, wl[(j+2)*OUT_C + o]);  fma_hi(acc, u.y, wl[(j+3)*OUT_C + o]);
        fma_lo(acc, u.z, wl[(j+4)*OUT_C + o]);  fma_hi(acc, u.z, wl[(j+5)*OUT_C + o]);
        fma_lo(acc, u.w, wl[(j+6)*OUT_C + o]);  fma_hi(acc, u.w, wl[(j+7)*OUT_C + o]);
    }
    const uint4* c = (const uint4*)(r2 + (size_t)row * 128);
#pragma unroll
    for (int q = 0; q < 16; ++q) {
        uint4 u = c[q]; int j = 96 + q * 8;
        fma_lo(acc, u.x, wl[(j+0)*OUT_C + o]);  fma_hi(acc, u.x, wl[(j+1)*OUT_C + o]);
        fma_lo(acc, u.y, wl[(j+2)*OUT_C + o]);  fma_hi(acc, u.y, wl[(j+3)*OUT_C + o]);
        fma_lo(acc, u.z, wl[(j+4)*OUT_C + o]);  fma_hi(acc, u.z, wl[(j+5)*OUT_C + o]);
        fma_lo(acc, u.w, wl[(j+6)*OUT_C + o]);  fma_hi(acc, u.w, wl[(j+7)*OUT_C + o]);
    }
    out[(size_t)row * OUT_C + o] = acc;
}

// ---------------------------------------------------------------------------
extern "C" void kernel_launch(void* const* d_in, const int* in_sizes, int n_in,
                              void* d_out, int out_size, void* d_ws, size_t ws_size,
                              hipStream_t stream) {
    const float* x   = (const float*)d_in[0];
    const float* we  = (const float*)d_in[1];
    const float* wc  = (const float*)d_in[2];
    const int*   a1r = (const int*)  d_in[3];
    const int*   a1c = (const int*)  d_in[4];
    const float* a1v = (const float*)d_in[5];
    const int*   a2r = (const int*)  d_in[6];
    const int*   a2c = (const int*)  d_in[7];
    const float* a2v = (const float*)d_in[8];
    float* out = (float*)d_out;

    const int E1 = in_sizes[3];
    const int E2 = in_sizes[6];
    const int n  = in_sizes[0] / IN_C;   // 20000

    // Workspace (f16 features): r0[n*32] r1[n*64] r2[n*128], ip1/ip2, dummy
    ushort* r0 = (ushort*)d_ws;
    ushort* r1 = r0 + (size_t)n * 32;
    ushort* r2 = r1 + (size_t)n * 64;
    int*   ip1 = (int*)(r2 + (size_t)n * 128);
    int*   ip2 = ip1 + (n + 1);
    float* dummy = (float*)(ip2 + (n + 2));

    // 1) fused embed + indptr + A2 edge-list warm-touch
    {
        const int nbE = (n + 15) / 16;
        const int nbI = (n + 1 + 255) / 256;
        const int nbT = 512;
        prep_kernel<<<nbE + nbI + nbT, 256, 0, stream>>>(
            x, we, r0, a1r, E1, ip1, a2r, E2, ip2, a2c, a2v, dummy,
            n, nbE, nbI, nbT);
    }

    // 2) level 1: r1 = relu([A1 r0 | A2 r0]); C=32, ROWS=2 -> W=8, 8 rows/block
    {
        const int nb = (n + 7) / 8;
        spmm_level<32, 2><<<2 * nb, 256, 0, stream>>>(ip1, a1c, a1v, ip2, a2c, a2v,
                                                      r0, r1, n, nb);
    }
    // 3) level 2: r2 = relu([A1 r1 | A2 r1]); C=64, ROWS=1 -> W=8, 4 rows/block
    {
        const int nb = (n + 3) / 4;
        spmm_level<64, 1><<<2 * nb, 256, 0, stream>>>(ip1, a1c, a1v, ip2, a2c, a2v,
                                                      r1, r2, n, nb);
    }

    // 4) fused concat + classify
    classify_kernel<<<(n + 15) / 16, 256, 0, stream>>>(r0, r1, r2, wc, out, n);
}

// Round 2
// 211.095 us; speedup vs baseline: 1.0522x; 1.0522x over previous
//
#include <hip/hip_runtime.h>

typedef unsigned int uint;
typedef unsigned short ushort;

#define IN_C 128
#define HID  32

// ---- f16 helpers (fp32 accumulate everywhere; RNE on store) ---------------
__device__ __forceinline__ uint f2h2(float a, float b) {
    _Float16 ha = (_Float16)a, hb = (_Float16)b;
    unsigned short ua = __builtin_bit_cast(unsigned short, ha);
    unsigned short ub = __builtin_bit_cast(unsigned short, hb);
    return (uint)ua | ((uint)ub << 16);
}
// acc += f16_lo(pk) * v  -- single full-rate VOP3P v_fma_mix_f32, no unpack
__device__ __forceinline__ void fma_lo(float& acc, uint pk, float v) {
    asm("v_fma_mix_f32 %0, %1, %2, %0 op_sel:[0,0,0] op_sel_hi:[1,0,0]"
        : "+v"(acc) : "v"(pk), "v"(v));
}
// acc += f16_hi(pk) * v
__device__ __forceinline__ void fma_hi(float& acc, uint pk, float v) {
    asm("v_fma_mix_f32 %0, %1, %2, %0 op_sel:[1,0,0] op_sel_hi:[1,0,0]"
        : "+v"(acc) : "v"(pk), "v"(v));
}

// ---------------------------------------------------------------------------
// K1: fused prep (unchanged).
// ---------------------------------------------------------------------------
__global__ void prep_kernel(const float* __restrict__ x,
                            const float* __restrict__ w,
                            ushort* __restrict__ r0,
                            const int* __restrict__ a1r, int E1, int* __restrict__ ip1,
                            const int* __restrict__ a2r, int E2, int* __restrict__ ip2,
                            const int* __restrict__ a2c, const float* __restrict__ a2v,
                            float* __restrict__ dummy,
                            int n, int nbE, int nbI, int nbT) {
    __shared__ float wl[IN_C * HID];
    const int tid = threadIdx.x;
    if (blockIdx.x < nbE) {
        for (int i = tid; i < IN_C * HID; i += blockDim.x) wl[i] = w[i];
        __syncthreads();
        const int row = blockIdx.x * 16 + tid / 16;
        const int h0  = (tid % 16) * 2;
        if (row >= n) return;
        const float4* xr = (const float4*)(x + (size_t)row * IN_C);
        float a0 = 0.f, a1 = 0.f;
#pragma unroll
        for (int k4 = 0; k4 < IN_C / 4; ++k4) {
            float4 xv = xr[k4];
            a0 += xv.x * wl[(4*k4+0)*HID + h0];  a1 += xv.x * wl[(4*k4+0)*HID + h0+1];
            a0 += xv.y * wl[(4*k4+1)*HID + h0];  a1 += xv.y * wl[(4*k4+1)*HID + h0+1];
            a0 += xv.z * wl[(4*k4+2)*HID + h0];  a1 += xv.z * wl[(4*k4+2)*HID + h0+1];
            a0 += xv.w * wl[(4*k4+3)*HID + h0];  a1 += xv.w * wl[(4*k4+3)*HID + h0+1];
        }
        uint p = f2h2(fmaxf(a0, 0.f), fmaxf(a1, 0.f));
        ((uint*)r0)[(size_t)row * 16 + (tid % 16)] = p;
    } else if (blockIdx.x < nbE + nbI) {
        const int i = (blockIdx.x - nbE) * 256 + tid;
        if (i > n) return;
        int lo = 0, hi = E1;
        while (lo < hi) { int m = (lo + hi) >> 1; if (a1r[m] < i) lo = m + 1; else hi = m; }
        ip1[i] = lo;
        lo = 0; hi = E2;
        while (lo < hi) { int m = (lo + hi) >> 1; if (a2r[m] < i) lo = m + 1; else hi = m; }
        ip2[i] = lo;
    } else {
        const int t = (blockIdx.x - nbE - nbI) * 256 + tid;
        const int stride = nbT * 256;
        const int total4 = E2 / 4;
        const float4* c4 = (const float4*)a2c;
        const float4* v4 = (const float4*)a2v;
        float s = 0.f;
        for (int i = t; i < total4; i += stride) {
            float4 u = c4[i], v = v4[i];
            s += u.x + u.y + u.z + u.w + v.x + v.y + v.z + v.w;
        }
        if (s == 123.456f) dummy[0] = s;   // never true in practice; defeats DCE
    }
}

// ---------------------------------------------------------------------------
// K2: fused-level SpMM + ReLU, f16 features / fp32 accumulate (v_fma_mix).
// Latency-bound fix (R2): explicit software pipeline.
//   Heavy path (A2 rows, deg~205): 4-edge batches; edge batches prefetched
//   2 ahead, gathers issued 1 batch ahead -> waits are on 1-iteration-old
//   loads (counted vmcnt, never a full chain per iteration).
//   Light path (A1 rows, deg~15 < 4*W): per-edge way-strided loop with
//   col/val prefetched 1 ahead and gather pipelined 1 ahead (the old code
//   pushed ALL these edges through a fully serial scalar tail).
// Blocks [0,nb2) = A2 (out col off C); rest = A1 (off 0).
// ---------------------------------------------------------------------------
template <int C, int ROWS>
__global__ __launch_bounds__(256) void spmm_level(
        const int* __restrict__ ip1, const int* __restrict__ col1,
        const float* __restrict__ val1,
        const int* __restrict__ ip2, const int* __restrict__ col2,
        const float* __restrict__ val2,
        const ushort* __restrict__ xin, ushort* __restrict__ out,
        int n, int nb2) {
    constexpr int L    = C / 8;        // feature lanes per row
    constexpr int SUBL = 64 / ROWS;    // lanes per row
    constexpr int W    = SUBL / L;     // edge ways per row
    const int lane = threadIdx.x & 63;
    const int wave = threadIdx.x >> 6;
    const int sub  = lane / SUBL;
    const int li   = lane % SUBL;
    const int fl   = li % L;
    const int way  = li / L;

    int bid = blockIdx.x;
    const int* ip; const int* col; const float* val; int off; bool heavy;
    if (bid < nb2) {             ip = ip2; col = col2; val = val2; off = C; heavy = true;  }
    else           { bid -= nb2; ip = ip1; col = col1; val = val1; off = 0; heavy = false; }

    const int row = (bid * 4 + wave) * ROWS + sub;
    if (row >= n) return;

    const uint flo = (uint)fl * 16u;   // byte offset of this lane's 8 feats
    float acc[8];
#pragma unroll
    for (int j = 0; j < 8; ++j) acc[j] = 0.f;

    auto gat = [&](uint c) -> uint4 {
        return *(const uint4*)((const char*)xin + (c * (uint)(2 * C) + flo));
    };
    auto fmadd = [&](const uint4& u, float v) {
        fma_lo(acc[0], u.x, v); fma_hi(acc[1], u.x, v);
        fma_lo(acc[2], u.y, v); fma_hi(acc[3], u.y, v);
        fma_lo(acc[4], u.z, v); fma_hi(acc[5], u.z, v);
        fma_lo(acc[6], u.w, v); fma_hi(acc[7], u.w, v);
    };

    const int s = ip[row];
    const int e = ip[row + 1];

    if (heavy) {
        int sv = (s + 3) & ~3; if (sv > e) sv = e;     // 16B-align vector loads
        const int nv = (e > sv) ? (e - sv) / (4 * W) : 0;

        // unaligned head (<=3 edges)
        for (int idx = s + way; idx < sv; idx += W) fmadd(gat((uint)col[idx]), val[idx]);

        const int*   cb = col + sv;
        const float* vb = val + sv;
        if (nv > 0) {
            auto eboff = [&](int i) {           // clamped batch byte-offset
                int ii = (i < nv) ? i : (nv - 1);
                return (ii * W + way) * 4;
            };
            // prologue: edges for batch 0 and 1; gathers for batch 0
            int b0 = eboff(0);
            int4   cA = *(const int4*)  (cb + b0);
            float4 vA = *(const float4*)(vb + b0);
            int b1 = eboff(1);
            int4   cB = *(const int4*)  (cb + b1);
            float4 vB = *(const float4*)(vb + b1);
            uint4 gA0 = gat((uint)cA.x), gA1 = gat((uint)cA.y),
                  gA2 = gat((uint)cA.z), gA3 = gat((uint)cA.w);
            for (int i = 0; i < nv; ++i) {
                // prefetch edges i+2 (clamped; redundant at tail, harmless)
                int b2 = eboff(i + 2);
                int4   cC = *(const int4*)  (cb + b2);
                float4 vC = *(const float4*)(vb + b2);
                // issue gathers for batch i+1 (cB loaded 2 iterations ago)
                uint4 gB0 = gat((uint)cB.x), gB1 = gat((uint)cB.y),
                      gB2 = gat((uint)cB.z), gB3 = gat((uint)cB.w);
                // consume batch i (gA issued last iteration -> counted wait,
                // cC/vC/gB stay in flight)
                fmadd(gA0, vA.x); fmadd(gA1, vA.y);
                fmadd(gA2, vA.z); fmadd(gA3, vA.w);
                // rotate
                gA0 = gB0; gA1 = gB1; gA2 = gB2; gA3 = gB3;
                cB = cC; vA = vB; vB = vC;
            }
        }
        // scalar tail (<= 4*W-1 edges across ways)
        for (int idx = sv + nv * 4 * W + way; idx < e; idx += W)
            fmadd(gat((uint)col[idx]), val[idx]);
    } else {
        // light rows: per-edge way-strided, pipelined depth-1 on col/val+gather
        int idx0 = s + way;
        if (idx0 < e) {
            int c0 = col[idx0]; float v0 = val[idx0];
            int idx1 = idx0 + W;
            int c1 = 0; float v1 = 0.f;
            if (idx1 < e) { c1 = col[idx1]; v1 = val[idx1]; }
            uint4 g0 = gat((uint)c0);
            while (true) {
                // prefetch edge 2 ahead
                int idx2 = idx1 + W;
                int c2 = 0; float v2 = 0.f;
                if (idx2 < e) { c2 = col[idx2]; v2 = val[idx2]; }
                // issue gather for next edge (c1=0 if past end: harmless row 0)
                uint4 g1 = gat((uint)c1);
                // consume current
                fmadd(g0, v0);
                if (idx1 >= e) break;
                g0 = g1; c1 = c2; v0 = v1; v1 = v2;
                idx1 = idx2;
            }
        }
    }

    // cross-way in-register reduction (stays within each row's subgroup)
#pragma unroll
    for (int m = L; m < SUBL; m <<= 1)
#pragma unroll
        for (int j = 0; j < 8; ++j) acc[j] += __shfl_xor(acc[j], m, 64);

    if (way == 0) {
        uint4 p;
        p.x = f2h2(fmaxf(acc[0], 0.f), fmaxf(acc[1], 0.f));
        p.y = f2h2(fmaxf(acc[2], 0.f), fmaxf(acc[3], 0.f));
        p.z = f2h2(fmaxf(acc[4], 0.f), fmaxf(acc[5], 0.f));
        p.w = f2h2(fmaxf(acc[6], 0.f), fmaxf(acc[7], 0.f));
        *(uint4*)(out + (size_t)row * (2 * C) + off + fl * 8) = p;
    }
}

// ---------------------------------------------------------------------------
// K3: out = [r0 | r1 | r2] @ w_classify  (f16 features via v_fma_mix,
// fp32 weights in LDS)
// ---------------------------------------------------------------------------
#define CDIM 224
#define OUT_C 16
__global__ void classify_kernel(const ushort* __restrict__ r0,
                                const ushort* __restrict__ r1,
                                const ushort* __restrict__ r2,
                                const float* __restrict__ w,
                                float* __restrict__ out, int n) {
    __shared__ float wl[CDIM * OUT_C];
    const int tid = threadIdx.x;
    for (int i = tid; i < CDIM * OUT_C; i += blockDim.x) wl[i] = w[i];
    __syncthreads();
    const int row = blockIdx.x * 16 + tid / 16;
    const int o   = tid % 16;
    if (row >= n) return;
    float acc = 0.f;

    const uint4* a = (const uint4*)(r0 + (size_t)row * 32);
#pragma unroll
    for (int q = 0; q < 4; ++q) {
        uint4 u = a[q]; int j = q * 8;
        fma_lo(acc, u.x, wl[(j+0)*OUT_C + o]);  fma_hi(acc, u.x, wl[(j+1)*OUT_C + o]);
        fma_lo(acc, u.y, wl[(j+2)*OUT_C + o]);  fma_hi(acc, u.y, wl[(j+3)*OUT_C + o]);
        fma_lo(acc, u.z, wl[(j+4)*OUT_C + o]);  fma_hi(acc, u.z, wl[(j+5)*OUT_C + o]);
        fma_lo(acc, u.w, wl[(j+6)*OUT_C + o]);  fma_hi(acc, u.w, wl[(j+7)*OUT_C + o]);
    }
    const uint4* b = (const uint4*)(r1 + (size_t)row * 64);
#pragma unroll
    for (int q = 0; q < 8; ++q) {
        uint4 u = b[q]; int j = 32 + q * 8;
        fma_lo(acc, u.x, wl[(j+0)*OUT_C + o]);  fma_hi(acc, u.x, wl[(j+1)*OUT_C + o]);
        fma_lo(acc, u.y, wl[(j+2)*OUT_C + o]);  fma_hi(acc, u.y, wl[(j+3)*OUT_C + o]);
        fma_lo(acc, u.z, wl[(j+4)*OUT_C + o]);  fma_hi(acc, u.z, wl[(j+5)*OUT_C + o]);
        fma_lo(acc, u.w, wl[(j+6)*OUT_C + o]);  fma_hi(acc, u.w, wl[(j+7)*OUT_C + o]);
    }
    const uint4* c = (const uint4*)(r2 + (size_t)row * 128);
#pragma unroll
    for (int q = 0; q < 16; ++q) {
        uint4 u = c[q]; int j = 96 + q * 8;
        fma_lo(acc, u.x, wl[(j+0)*OUT_C + o]);  fma_hi(acc, u.x, wl[(j+1)*OUT_C + o]);
        fma_lo(acc, u.y, wl[(j+2)*OUT_C + o]);  fma_hi(acc, u.y, wl[(j+3)*OUT_C + o]);
        fma_lo(acc, u.z, wl[(j+4)*OUT_C + o]);  fma_hi(acc, u.z, wl[(j+5)*OUT_C + o]);
        fma_lo(acc, u.w, wl[(j+6)*OUT_C + o]);  fma_hi(acc, u.w, wl[(j+7)*OUT_C + o]);
    }
    out[(size_t)row * OUT_C + o] = acc;
}

// ---------------------------------------------------------------------------
extern "C" void kernel_launch(void* const* d_in, const int* in_sizes, int n_in,
                              void* d_out, int out_size, void* d_ws, size_t ws_size,
                              hipStream_t stream) {
    const float* x   = (const float*)d_in[0];
    const float* we  = (const float*)d_in[1];
    const float* wc  = (const float*)d_in[2];
    const int*   a1r = (const int*)  d_in[3];
    const int*   a1c = (const int*)  d_in[4];
    const float* a1v = (const float*)d_in[5];
    const int*   a2r = (const int*)  d_in[6];
    const int*   a2c = (const int*)  d_in[7];
    const float* a2v = (const float*)d_in[8];
    float* out = (float*)d_out;

    const int E1 = in_sizes[3];
    const int E2 = in_sizes[6];
    const int n  = in_sizes[0] / IN_C;   // 20000

    // Workspace (f16 features): r0[n*32] r1[n*64] r2[n*128], ip1/ip2, dummy
    ushort* r0 = (ushort*)d_ws;
    ushort* r1 = r0 + (size_t)n * 32;
    ushort* r2 = r1 + (size_t)n * 64;
    int*   ip1 = (int*)(r2 + (size_t)n * 128);
    int*   ip2 = ip1 + (n + 1);
    float* dummy = (float*)(ip2 + (n + 2));

    // 1) fused embed + indptr + A2 edge-list warm-touch
    {
        const int nbE = (n + 15) / 16;
        const int nbI = (n + 1 + 255) / 256;
        const int nbT = 512;
        prep_kernel<<<nbE + nbI + nbT, 256, 0, stream>>>(
            x, we, r0, a1r, E1, ip1, a2r, E2, ip2, a2c, a2v, dummy,
            n, nbE, nbI, nbT);
    }

    // 2) level 1: r1 = relu([A1 r0 | A2 r0]); C=32, ROWS=2 -> W=8, 8 rows/block
    {
        const int nb = (n + 7) / 8;
        spmm_level<32, 2><<<2 * nb, 256, 0, stream>>>(ip1, a1c, a1v, ip2, a2c, a2v,
                                                      r0, r1, n, nb);
    }
    // 3) level 2: r2 = relu([A1 r1 | A2 r1]); C=64, ROWS=1 -> W=8, 4 rows/block
    {
        const int nb = (n + 3) / 4;
        spmm_level<64, 1><<<2 * nb, 256, 0, stream>>>(ip1, a1c, a1v, ip2, a2c, a2v,
                                                      r1, r2, n, nb);
    }

    // 4) fused concat + classify
    classify_kernel<<<(n + 15) / 16, 256, 0, stream>>>(r0, r1, r2, wc, out, n);
}